// Round 11
// baseline (460.619 us; speedup 1.0000x reference)
//
#include <hip/hip_runtime.h>

namespace {
constexpr int CH = 640, HW = 25, MS = 125;
constexpr int CHW = CH * HW;    // 16000
constexpr float GAMMA = 20.f, GAMMA2 = 10.f;
constexpr float EPS = 1e-12f;
}

// Shot-mean + L2-normalize (over c) + transpose to sup_t[b][nk][c]. (proven)
__global__ __launch_bounds__(256)
void prep_sup_kernel(const float* __restrict__ sup, float* __restrict__ sup_t) {
  __shared__ __align__(16) float m[CHW];   // mean tile [c][k]
  __shared__ float inv[HW];
  const int bn = blockIdx.x;               // b*5 + n
  const float* base = sup + (size_t)(bn / 5) * (25 * CHW)
                          + (size_t)(bn % 5) * (5 * CHW);
  for (int idx = threadIdx.x; idx < CHW; idx += 256) {
    float s = 0.f;
    #pragma unroll
    for (int sh = 0; sh < 5; ++sh) s += base[sh * CHW + idx];
    m[idx] = s * 0.2f;
  }
  __syncthreads();
  {
    int i = threadIdx.x >> 3, s8 = threadIdx.x & 7;
    if (i < HW) {
      float p = 0.f;
      for (int c = s8; c < CH; c += 8) { float v = m[c * HW + i]; p += v * v; }
      p += __shfl_xor(p, 1); p += __shfl_xor(p, 2); p += __shfl_xor(p, 4);
      if (s8 == 0) inv[i] = rsqrtf(p + EPS);
    }
  }
  __syncthreads();
  float* outp = sup_t + (size_t)bn * CHW;  // [nk][c], coalesced writes
  for (int idx = threadIdx.x; idx < CHW; idx += 256) {
    int k = idx / CH, c = idx - k * CH;
    outp[idx] = m[c * HW + k] * inv[k];
  }
}

// One block per (b, 5-query group): 125x125 S GEMM (8x8 reg tiles, r9-verbatim) ->
// per-query softmax/BA -> BATCHED f64 Katz solves -> ks re-scatter -> outputs.
__global__ __launch_bounds__(256)
void melmask_kernel(const float* __restrict__ qry, const float* __restrict__ sup_t,
                    float* __restrict__ out) {
  __shared__ __align__(16) float pool[4224]; // atile[16][132]|btile[16][132]; Qm; ksf
  __shared__ __align__(16) float Sld[3136];  // per-query S[r][col] stride 125; in-place P
  __shared__ double Msol5[3375];             // 5 systems x (25x26 aug, stride 27)
  __shared__ float invq_s[128], rmaxs[128], rsis[128];
  __shared__ float x5[5 * 32];               // solutions
  __shared__ float kqs[32];

  float* atile = pool;
  float* btile = pool + 2112;
  float* Qm    = pool;                       // overlays staging after GEMM
  float* ksf   = pool;                       // overlays Qm after the solve

  const int tid = threadIdx.x;
  // XCD swizzle: 480 = 8*60; same-XCD blocks share 4 consecutive b's.
  const int Bl = (blockIdx.x & 7) * 60 + (blockIdx.x >> 3);
  const int b = Bl / 15, qg = Bl - 15 * b;
  const float* qbase = qry + ((size_t)b * 75 + (size_t)qg * 5) * CHW;
  const float* sbase = sup_t + (size_t)b * (MS * CH);
  const int ty = tid >> 4, tx = tid & 15;    // rows {4ty+u, 64+4ty+u}, cols {4tx+v, 64+4tx+v}

  float acc[2][2][4][4];
  #pragma unroll
  for (int g = 0; g < 2; ++g)
    #pragma unroll
    for (int h = 0; h < 2; ++h)
      #pragma unroll
      for (int u = 0; u < 4; ++u)
        #pragma unroll
        for (int v = 0; v < 4; ++v) acc[g][h][u][v] = 0.f;
  float npart = 0.f;

  for (int c0 = 0; c0 < CH; c0 += 16) {
    __syncthreads();                         // protect staging from prev readers
    #pragma unroll
    for (int mm = 0; mm < 8; ++mm) {         // A: 16k x 128row
      int idx = tid + 256 * mm;
      int k = idx >> 7, row = idx & 127;
      float v = 0.f;
      if (row < MS) {
        int qq = row / 25, i = row - 25 * qq;
        v = qbase[(size_t)qq * CHW + (size_t)(c0 + k) * 25 + i];
      }
      atile[k * 132 + row] = v;
    }
    #pragma unroll
    for (int mm = 0; mm < 2; ++mm) {         // B: 16k x 128col (transpose via float4)
      int idx = tid + 256 * mm;
      int col = idx >> 2, kq = idx & 3;
      float4 v = make_float4(0.f, 0.f, 0.f, 0.f);
      if (col < MS) v = *(const float4*)(sbase + (size_t)col * CH + c0 + 4 * kq);
      btile[(4 * kq + 0) * 132 + col] = v.x;
      btile[(4 * kq + 1) * 132 + col] = v.y;
      btile[(4 * kq + 2) * 132 + col] = v.z;
      btile[(4 * kq + 3) * 132 + col] = v.w;
    }
    __syncthreads();
    if (tid < MS) {                          // query inv-norm accumulation
      #pragma unroll
      for (int k = 0; k < 16; ++k) { float v = atile[k * 132 + tid]; npart += v * v; }
    }
    #pragma unroll
    for (int k = 0; k < 16; ++k) {
      const float4 a0 = *(const float4*)&atile[k * 132 + 4 * ty];
      const float4 a1 = *(const float4*)&atile[k * 132 + 64 + 4 * ty];
      const float4 b0 = *(const float4*)&btile[k * 132 + 4 * tx];
      const float4 b1 = *(const float4*)&btile[k * 132 + 64 + 4 * tx];
      const float ag[2][4] = {{a0.x, a0.y, a0.z, a0.w}, {a1.x, a1.y, a1.z, a1.w}};
      const float bg[2][4] = {{b0.x, b0.y, b0.z, b0.w}, {b1.x, b1.y, b1.z, b1.w}};
      #pragma unroll
      for (int g = 0; g < 2; ++g)
        #pragma unroll
        for (int u = 0; u < 4; ++u)
          #pragma unroll
          for (int h = 0; h < 2; ++h)
            #pragma unroll
            for (int v = 0; v < 4; ++v) acc[g][h][u][v] += ag[g][u] * bg[h][v];
    }
  }
  if (tid < MS) invq_s[tid] = rsqrtf(npart + EPS);
  __syncthreads();

  // ---- loop 1: per query, softmaxes + BA -> Msol5[qq] ----
  for (int qq = 0; qq < 5; ++qq) {
    const int r0 = qq * 25;
    #pragma unroll
    for (int g = 0; g < 2; ++g)
      #pragma unroll
      for (int u = 0; u < 4; ++u) {
        const int row = g * 64 + 4 * ty + u;
        if (row >= r0 && row < r0 + 25) {
          const int r = row - r0;
          const float iv = invq_s[row];
          #pragma unroll
          for (int h = 0; h < 2; ++h)
            #pragma unroll
            for (int v = 0; v < 4; ++v) {
              const int col = h * 64 + 4 * tx + v;
              if (col < MS) Sld[r * MS + col] = acc[g][h][u][v] * iv;
            }
        }
      }
    __syncthreads();

    // column softmax with GAMMA2 -> Qm[col][i]
    if (tid < MS) {
      float mx = -1e30f;
      #pragma unroll
      for (int i = 0; i < HW; ++i) mx = fmaxf(mx, Sld[i * MS + tid]);
      float e[HW]; float sum = 0.f;
      #pragma unroll
      for (int i = 0; i < HW; ++i) { e[i] = __expf(GAMMA2 * (Sld[i * MS + tid] - mx)); sum += e[i]; }
      float is = 1.f / sum;
      #pragma unroll
      for (int i = 0; i < HW; ++i) Qm[tid * HW + i] = e[i] * is;
    }
    __syncthreads();

    // row softmax with GAMMA, in place -> P; persist per-row stats
    {
      int i = tid >> 3, s8 = tid & 7;
      if (i < HW) {
        float mx = -1e30f;
        for (int j = s8; j < MS; j += 8) mx = fmaxf(mx, Sld[i * MS + j]);
        mx = fmaxf(mx, __shfl_xor(mx, 1));
        mx = fmaxf(mx, __shfl_xor(mx, 2));
        mx = fmaxf(mx, __shfl_xor(mx, 4));
        float sum = 0.f;
        for (int j = s8; j < MS; j += 8) {
          float e = __expf(GAMMA * (Sld[i * MS + j] - mx));
          Sld[i * MS + j] = e; sum += e;
        }
        sum += __shfl_xor(sum, 1); sum += __shfl_xor(sum, 2); sum += __shfl_xor(sum, 4);
        float is = 1.f / sum;
        for (int j = s8; j < MS; j += 8) Sld[i * MS + j] *= is;
        if (s8 == 0) { rmaxs[r0 + i] = mx; rsis[r0 + i] = is; }
      }
    }
    __syncthreads();

    // BA (+ B*1 via i2==25) -> Msol5[qq] directly (no alias)
    #pragma unroll
    for (int t = 0; t < 3; ++t) {
      const int pp = tid + 256 * t;
      if (pp < 650) {
        const int i = pp / 26, i2 = pp - 26 * i;
        float s = 0.f;
        if (i2 < 25) {
          for (int j = 0; j < MS; ++j) s += Qm[j * HW + i] * Sld[i2 * MS + j];
          Msol5[qq * 675 + i * 27 + i2] = (i == i2 ? 1.0 : 0.0) - 0.998001 * (double)s;
        } else {
          for (int j = 0; j < MS; ++j) s += Qm[j * HW + i];
          Msol5[qq * 675 + i * 27 + 25] = 1.0 + 0.999 * (double)s;
        }
      }
    }
    __syncthreads();   // Sld/Qm reuse fence for next query
  }

  // ---- batched Gaussian elimination: thread (s=tid>>5, i=tid&31), 5 systems ----
  {
    const int s = tid >> 5, i = tid & 31;
    for (int k = 0; k < 24; ++k) {
      if (s < 5 && i > k && i < HW) {
        double* M = Msol5 + 675 * s;
        const double f = M[i * 27 + k] / M[k * 27 + k];
        for (int j = k + 1; j <= 25; ++j) M[i * 27 + j] -= f * M[k * 27 + j];
      }
      __syncthreads();
    }
    for (int k = 24; k >= 0; --k) {
      if (s < 5 && i <= k) {
        double* M = Msol5 + 675 * s;
        const double xk = M[k * 27 + 25] / M[k * 27 + k];
        if (i == k) x5[s * 32 + k] = (float)xk;
        else        M[i * 27 + 25] -= M[i * 27 + k] * xk;
      }
      __syncthreads();
    }
  }

  // ---- loop 2: per query, re-scatter P from acc and produce outputs ----
  for (int qq = 0; qq < 5; ++qq) {
    const int r0 = qq * 25;
    const int bq = b * 75 + qg * 5 + qq;
    #pragma unroll
    for (int g = 0; g < 2; ++g)
      #pragma unroll
      for (int u = 0; u < 4; ++u) {
        const int row = g * 64 + 4 * ty + u;
        if (row >= r0 && row < r0 + 25) {
          const int r = row - r0;
          const float iv = invq_s[row], rm = rmaxs[row], rs = rsis[row];
          #pragma unroll
          for (int h = 0; h < 2; ++h)
            #pragma unroll
            for (int v = 0; v < 4; ++v) {
              const int col = h * 64 + 4 * tx + v;
              if (col < MS)
                Sld[r * MS + col] = __expf(GAMMA * (acc[g][h][u][v] * iv - rm)) * rs;
            }
        }
      }
    __syncthreads();
    if (tid < MS) {
      float sv = 0.f;
      #pragma unroll
      for (int i = 0; i < HW; ++i) sv += Sld[i * MS + tid] * x5[qq * 32 + i];
      ksf[tid] = 0.999f * sv;
    }
    if (tid < HW) kqs[tid] = x5[qq * 32 + tid] - 1.0f;
    __syncthreads();
    if (tid < HW) {
      float s = 0.f;
      #pragma unroll
      for (int i = 0; i < HW; ++i) s += kqs[i];
      out[(size_t)bq * HW + tid] = kqs[tid] / s;
    }
    if (tid < MS) {
      const int n = tid / HW;
      float s = 0.f;
      #pragma unroll
      for (int k2 = 0; k2 < HW; ++k2) s += ksf[n * HW + k2];
      out[60000 + (size_t)bq * MS + tid] = ksf[tid] / s;
    }
    __syncthreads();   // Sld/ksf reuse fence
  }
}

extern "C" void kernel_launch(void* const* d_in, const int* in_sizes, int n_in,
                              void* d_out, int out_size, void* d_ws, size_t ws_size,
                              hipStream_t stream) {
  const float* sup = (const float*)d_in[0];
  const float* qry = (const float*)d_in[1];
  float* outp = (float*)d_out;
  float* sup_t = (float*)d_ws;             // 32*125*640*4 = 10.24 MB (proven fit)
  prep_sup_kernel<<<160, 256, 0, stream>>>(sup, sup_t);
  melmask_kernel<<<480, 256, 0, stream>>>(qry, sup_t, outp);
}

// Round 12
// 320.029 us; speedup vs baseline: 1.4393x; 1.4393x over previous
//
#include <hip/hip_runtime.h>

namespace {
constexpr int CH = 640, HW = 25, MS = 125;
constexpr int CHW = CH * HW;    // 16000
constexpr float GAMMA = 20.f, GAMMA2 = 10.f;
constexpr float EPS = 1e-12f;
}

// Shot-mean + L2-normalize (over c) + transpose to sup_t[b][nk][c]. (proven)
__global__ __launch_bounds__(256)
void prep_sup_kernel(const float* __restrict__ sup, float* __restrict__ sup_t) {
  __shared__ __align__(16) float m[CHW];   // mean tile [c][k]
  __shared__ float inv[HW];
  const int bn = blockIdx.x;               // b*5 + n
  const float* base = sup + (size_t)(bn / 5) * (25 * CHW)
                          + (size_t)(bn % 5) * (5 * CHW);
  for (int idx = threadIdx.x; idx < CHW; idx += 256) {
    float s = 0.f;
    #pragma unroll
    for (int sh = 0; sh < 5; ++sh) s += base[sh * CHW + idx];
    m[idx] = s * 0.2f;
  }
  __syncthreads();
  {
    int i = threadIdx.x >> 3, s8 = threadIdx.x & 7;
    if (i < HW) {
      float p = 0.f;
      for (int c = s8; c < CH; c += 8) { float v = m[c * HW + i]; p += v * v; }
      p += __shfl_xor(p, 1); p += __shfl_xor(p, 2); p += __shfl_xor(p, 4);
      if (s8 == 0) inv[i] = rsqrtf(p + EPS);
    }
  }
  __syncthreads();
  float* outp = sup_t + (size_t)bn * CHW;  // [nk][c], coalesced writes
  for (int idx = threadIdx.x; idx < CHW; idx += 256) {
    int k = idx / CH, c = idx - k * CH;
    outp[idx] = m[c * HW + k] * inv[k];
  }
}

// One block per (b, 5-query group): 125x125 S GEMM (8x8 reg tiles) ->
// per-query softmaxes -> BA -> wave-synchronous f64 Katz solve -> outputs.
__global__ __launch_bounds__(256)
void melmask_kernel(const float* __restrict__ qry, const float* __restrict__ sup_t,
                    float* __restrict__ out) {
  __shared__ __align__(16) float pool[4224]; // atile[16][132] | btile[16][132]; Qm overlay
  __shared__ __align__(16) float Sld[3125];  // per-query S[r][col] stride 125; in-place P
  __shared__ double Msol[675];               // augmented 25x26, stride 27
  __shared__ double xsd[HW];
  __shared__ float invq_s[128];
  __shared__ float kqs[HW];
  __shared__ float ksf[MS];

  float* atile = pool;
  float* btile = pool + 2112;
  float* Qm    = pool;                       // overlays staging after GEMM

  const int tid = threadIdx.x;
  // XCD swizzle: 480 = 8*60; same-XCD blocks share 4 consecutive b's (B panel L2-resident).
  const int Bl = (blockIdx.x & 7) * 60 + (blockIdx.x >> 3);
  const int b = Bl / 15, qg = Bl - 15 * b;
  const float* qbase = qry + ((size_t)b * 75 + (size_t)qg * 5) * CHW;
  const float* sbase = sup_t + (size_t)b * (MS * CH);
  const int ty = tid >> 4, tx = tid & 15;    // rows {4ty+u, 64+4ty+u}, cols {4tx+v, 64+4tx+v}

  float acc[2][2][4][4];
  #pragma unroll
  for (int g = 0; g < 2; ++g)
    #pragma unroll
    for (int h = 0; h < 2; ++h)
      #pragma unroll
      for (int u = 0; u < 4; ++u)
        #pragma unroll
        for (int v = 0; v < 4; ++v) acc[g][h][u][v] = 0.f;
  float npart = 0.f;

  for (int c0 = 0; c0 < CH; c0 += 16) {
    __syncthreads();                         // protect staging from prev readers
    #pragma unroll
    for (int mm = 0; mm < 8; ++mm) {         // A: 16k x 128row
      int idx = tid + 256 * mm;
      int k = idx >> 7, row = idx & 127;
      float v = 0.f;
      if (row < MS) {
        int qq = row / 25, i = row - 25 * qq;
        v = qbase[(size_t)qq * CHW + (size_t)(c0 + k) * 25 + i];
      }
      atile[k * 132 + row] = v;
    }
    #pragma unroll
    for (int mm = 0; mm < 2; ++mm) {         // B: 16k x 128col (transpose via float4)
      int idx = tid + 256 * mm;
      int col = idx >> 2, kq = idx & 3;
      float4 v = make_float4(0.f, 0.f, 0.f, 0.f);
      if (col < MS) v = *(const float4*)(sbase + (size_t)col * CH + c0 + 4 * kq);
      btile[(4 * kq + 0) * 132 + col] = v.x;
      btile[(4 * kq + 1) * 132 + col] = v.y;
      btile[(4 * kq + 2) * 132 + col] = v.z;
      btile[(4 * kq + 3) * 132 + col] = v.w;
    }
    __syncthreads();
    if (tid < MS) {                          // query inv-norm accumulation
      #pragma unroll
      for (int k = 0; k < 16; ++k) { float v = atile[k * 132 + tid]; npart += v * v; }
    }
    #pragma unroll
    for (int k = 0; k < 16; ++k) {
      const float4 a0 = *(const float4*)&atile[k * 132 + 4 * ty];
      const float4 a1 = *(const float4*)&atile[k * 132 + 64 + 4 * ty];
      const float4 b0 = *(const float4*)&btile[k * 132 + 4 * tx];
      const float4 b1 = *(const float4*)&btile[k * 132 + 64 + 4 * tx];
      const float ag[2][4] = {{a0.x, a0.y, a0.z, a0.w}, {a1.x, a1.y, a1.z, a1.w}};
      const float bg[2][4] = {{b0.x, b0.y, b0.z, b0.w}, {b1.x, b1.y, b1.z, b1.w}};
      #pragma unroll
      for (int g = 0; g < 2; ++g)
        #pragma unroll
        for (int u = 0; u < 4; ++u)
          #pragma unroll
          for (int h = 0; h < 2; ++h)
            #pragma unroll
            for (int v = 0; v < 4; ++v) acc[g][h][u][v] += ag[g][u] * bg[h][v];
    }
  }
  if (tid < MS) invq_s[tid] = rsqrtf(npart + EPS);
  __syncthreads();

  for (int qq = 0; qq < 5; ++qq) {
    const int bq = b * 75 + qg * 5 + qq;
    const int r0 = qq * 25;
    // ---- scatter this query's S rows (normalized) into Sld ----
    #pragma unroll
    for (int g = 0; g < 2; ++g)
      #pragma unroll
      for (int u = 0; u < 4; ++u) {
        const int row = g * 64 + 4 * ty + u;
        if (row >= r0 && row < r0 + 25) {
          const int r = row - r0;
          const float iv = invq_s[row];
          #pragma unroll
          for (int h = 0; h < 2; ++h)
            #pragma unroll
            for (int v = 0; v < 4; ++v) {
              const int col = h * 64 + 4 * tx + v;
              if (col < MS) Sld[r * MS + col] = acc[g][h][u][v] * iv;
            }
        }
      }
    __syncthreads();

    // ---- column softmax with GAMMA2 -> Qm[col][i] ----
    if (tid < MS) {
      float mx = -1e30f;
      #pragma unroll
      for (int i = 0; i < HW; ++i) mx = fmaxf(mx, Sld[i * MS + tid]);
      float e[HW]; float sum = 0.f;
      #pragma unroll
      for (int i = 0; i < HW; ++i) { e[i] = __expf(GAMMA2 * (Sld[i * MS + tid] - mx)); sum += e[i]; }
      float is = 1.f / sum;
      #pragma unroll
      for (int i = 0; i < HW; ++i) Qm[tid * HW + i] = e[i] * is;
    }
    __syncthreads();

    // ---- row softmax with GAMMA, in place -> P ----
    {
      int i = tid >> 3, s8 = tid & 7;
      if (i < HW) {
        float mx = -1e30f;
        for (int j = s8; j < MS; j += 8) mx = fmaxf(mx, Sld[i * MS + j]);
        mx = fmaxf(mx, __shfl_xor(mx, 1));
        mx = fmaxf(mx, __shfl_xor(mx, 2));
        mx = fmaxf(mx, __shfl_xor(mx, 4));
        float sum = 0.f;
        for (int j = s8; j < MS; j += 8) {
          float e = __expf(GAMMA * (Sld[i * MS + j] - mx));
          Sld[i * MS + j] = e; sum += e;
        }
        sum += __shfl_xor(sum, 1); sum += __shfl_xor(sum, 2); sum += __shfl_xor(sum, 4);
        float is = 1.f / sum;
        for (int j = s8; j < MS; j += 8) Sld[i * MS + j] *= is;
      }
    }
    __syncthreads();
    float* P = Sld;

    // ---- BA (+ B*1 via i2==25) -> Msol directly ----
    #pragma unroll
    for (int t = 0; t < 3; ++t) {
      const int pp = tid + 256 * t;
      if (pp < 650) {
        const int i = pp / 26, i2 = pp - 26 * i;
        float s = 0.f;
        if (i2 < 25) {
          for (int j = 0; j < MS; ++j) s += Qm[j * HW + i] * P[i2 * MS + j];
          Msol[i * 27 + i2] = (i == i2 ? 1.0 : 0.0) - 0.998001 * (double)s;
        } else {
          for (int j = 0; j < MS; ++j) s += Qm[j * HW + i];
          Msol[i * 27 + 25] = 1.0 + 0.999 * (double)s;
        }
      }
    }
    __syncthreads();

    // ---- wave-synchronous f64 GE + back-substitution (wave 0, ZERO barriers) ----
    // One wave is lockstep; only LDS memory ordering is needed between steps.
    if (tid < 64) {
      for (int k = 0; k < 24; ++k) {
        const int nj = 25 - k;               // cols k+1..25
        const int ne = (24 - k) * nj;        // update elements
        const double invp = 1.0 / Msol[k * 27 + k];
        for (int e = tid; e < ne; e += 64) {
          const int i = k + 1 + e / nj;
          const int j = k + 1 + e - (e / nj) * nj;
          Msol[i * 27 + j] -= Msol[i * 27 + k] * invp * Msol[k * 27 + j];
        }
        __threadfence_block();               // lgkmcnt drain; wave-lockstep => no barrier
      }
      for (int k = 24; k >= 0; --k) {
        const double xk = Msol[k * 27 + 25] / Msol[k * 27 + k];
        if (tid == k) xsd[k] = xk;
        if (tid < k) Msol[tid * 27 + 25] -= Msol[tid * 27 + k] * xk;
        __threadfence_block();
      }
    }
    __syncthreads();

    // ---- outputs ----
    if (tid < HW) kqs[tid] = (float)(xsd[tid] - 1.0);
    if (tid < MS) {
      float a = 0.f;
      #pragma unroll
      for (int i = 0; i < HW; ++i) a += P[i * MS + tid] * (float)xsd[i];
      ksf[tid] = 0.999f * a;
    }
    __syncthreads();
    if (tid < HW) {
      float s = 0.f;
      #pragma unroll
      for (int i = 0; i < HW; ++i) s += kqs[i];
      out[(size_t)bq * HW + tid] = kqs[tid] / s;
    }
    if (tid < MS) {
      const int n = tid / HW;
      float s = 0.f;
      #pragma unroll
      for (int k2 = 0; k2 < HW; ++k2) s += ksf[n * HW + k2];
      out[60000 + (size_t)bq * MS + tid] = ksf[tid] / s;
    }
    __syncthreads();   // Sld/Qm/Msol reuse fence for next query
  }
}

extern "C" void kernel_launch(void* const* d_in, const int* in_sizes, int n_in,
                              void* d_out, int out_size, void* d_ws, size_t ws_size,
                              hipStream_t stream) {
  const float* sup = (const float*)d_in[0];
  const float* qry = (const float*)d_in[1];
  float* outp = (float*)d_out;
  float* sup_t = (float*)d_ws;             // 32*125*640*4 = 10.24 MB (proven fit)
  prep_sup_kernel<<<160, 256, 0, stream>>>(sup, sup_t);
  melmask_kernel<<<480, 256, 0, stream>>>(qry, sup_t, outp);
}

// Round 13
// 260.719 us; speedup vs baseline: 1.7667x; 1.2275x over previous
//
#include <hip/hip_runtime.h>

namespace {
constexpr int CH = 640, HW = 25, MS = 125;
constexpr int CHW = CH * HW;    // 16000
constexpr float GAMMA = 20.f, GAMMA2 = 10.f;
constexpr float EPS = 1e-12f;
}

// Shot-mean + L2-normalize (over c) + transpose to sup_t[b][nk][c]. (proven)
__global__ __launch_bounds__(256)
void prep_sup_kernel(const float* __restrict__ sup, float* __restrict__ sup_t) {
  __shared__ __align__(16) float m[CHW];   // mean tile [c][k]
  __shared__ float inv[HW];
  const int bn = blockIdx.x;               // b*5 + n
  const float* base = sup + (size_t)(bn / 5) * (25 * CHW)
                          + (size_t)(bn % 5) * (5 * CHW);
  for (int idx = threadIdx.x; idx < CHW; idx += 256) {
    float s = 0.f;
    #pragma unroll
    for (int sh = 0; sh < 5; ++sh) s += base[sh * CHW + idx];
    m[idx] = s * 0.2f;
  }
  __syncthreads();
  {
    int i = threadIdx.x >> 3, s8 = threadIdx.x & 7;
    if (i < HW) {
      float p = 0.f;
      for (int c = s8; c < CH; c += 8) { float v = m[c * HW + i]; p += v * v; }
      p += __shfl_xor(p, 1); p += __shfl_xor(p, 2); p += __shfl_xor(p, 4);
      if (s8 == 0) inv[i] = rsqrtf(p + EPS);
    }
  }
  __syncthreads();
  float* outp = sup_t + (size_t)bn * CHW;  // [nk][c], coalesced writes
  for (int idx = threadIdx.x; idx < CHW; idx += 256) {
    int k = idx / CH, c = idx - k * CH;
    outp[idx] = m[c * HW + k] * inv[k];
  }
}

// Phase 1: one block per (b, 5-query group). 125x125 S GEMM (r9-verbatim tiles),
// apply query inv-norm, write S to workspace [bq][25][128] (padded, coalesced).
__global__ __launch_bounds__(256)
void gemm_s_kernel(const float* __restrict__ qry, const float* __restrict__ sup_t,
                   float* __restrict__ Sout) {
  __shared__ __align__(16) float pool[4224]; // atile[16][132] | btile[16][132]
  __shared__ float invq_s[128];
  float* atile = pool;
  float* btile = pool + 2112;

  const int tid = threadIdx.x;
  // XCD swizzle: 480 = 8*60; same-XCD blocks share 4 consecutive b's.
  const int Bl = (blockIdx.x & 7) * 60 + (blockIdx.x >> 3);
  const int b = Bl / 15, qg = Bl - 15 * b;
  const float* qbase = qry + ((size_t)b * 75 + (size_t)qg * 5) * CHW;
  const float* sbase = sup_t + (size_t)b * (MS * CH);
  const int ty = tid >> 4, tx = tid & 15;

  float acc[2][2][4][4];
  #pragma unroll
  for (int g = 0; g < 2; ++g)
    #pragma unroll
    for (int h = 0; h < 2; ++h)
      #pragma unroll
      for (int u = 0; u < 4; ++u)
        #pragma unroll
        for (int v = 0; v < 4; ++v) acc[g][h][u][v] = 0.f;
  float npart = 0.f;

  for (int c0 = 0; c0 < CH; c0 += 16) {
    __syncthreads();
    #pragma unroll
    for (int mm = 0; mm < 8; ++mm) {         // A: 16k x 128row
      int idx = tid + 256 * mm;
      int k = idx >> 7, row = idx & 127;
      float v = 0.f;
      if (row < MS) {
        int qq = row / 25, i = row - 25 * qq;
        v = qbase[(size_t)qq * CHW + (size_t)(c0 + k) * 25 + i];
      }
      atile[k * 132 + row] = v;
    }
    #pragma unroll
    for (int mm = 0; mm < 2; ++mm) {         // B: 16k x 128col (transpose via float4)
      int idx = tid + 256 * mm;
      int col = idx >> 2, kq = idx & 3;
      float4 v = make_float4(0.f, 0.f, 0.f, 0.f);
      if (col < MS) v = *(const float4*)(sbase + (size_t)col * CH + c0 + 4 * kq);
      btile[(4 * kq + 0) * 132 + col] = v.x;
      btile[(4 * kq + 1) * 132 + col] = v.y;
      btile[(4 * kq + 2) * 132 + col] = v.z;
      btile[(4 * kq + 3) * 132 + col] = v.w;
    }
    __syncthreads();
    if (tid < MS) {
      #pragma unroll
      for (int k = 0; k < 16; ++k) { float v = atile[k * 132 + tid]; npart += v * v; }
    }
    #pragma unroll
    for (int k = 0; k < 16; ++k) {
      const float4 a0 = *(const float4*)&atile[k * 132 + 4 * ty];
      const float4 a1 = *(const float4*)&atile[k * 132 + 64 + 4 * ty];
      const float4 b0 = *(const float4*)&btile[k * 132 + 4 * tx];
      const float4 b1 = *(const float4*)&btile[k * 132 + 64 + 4 * tx];
      const float ag[2][4] = {{a0.x, a0.y, a0.z, a0.w}, {a1.x, a1.y, a1.z, a1.w}};
      const float bg[2][4] = {{b0.x, b0.y, b0.z, b0.w}, {b1.x, b1.y, b1.z, b1.w}};
      #pragma unroll
      for (int g = 0; g < 2; ++g)
        #pragma unroll
        for (int u = 0; u < 4; ++u)
          #pragma unroll
          for (int h = 0; h < 2; ++h)
            #pragma unroll
            for (int v = 0; v < 4; ++v) acc[g][h][u][v] += ag[g][u] * bg[h][v];
    }
  }
  if (tid < MS) invq_s[tid] = rsqrtf(npart + EPS);
  __syncthreads();

  float* Sg = Sout + (size_t)(b * 75 + qg * 5) * 3200;  // per-query 25*128
  #pragma unroll
  for (int g = 0; g < 2; ++g)
    #pragma unroll
    for (int u = 0; u < 4; ++u) {
      const int row = g * 64 + 4 * ty + u;
      if (row < MS) {
        const float iv = invq_s[row];
        const int qq = row / 25, r = row - 25 * qq;
        #pragma unroll
        for (int h = 0; h < 2; ++h) {
          float4 val;                        // cols 125..127 are padding (B zeros)
          val.x = acc[g][h][u][0] * iv;
          val.y = acc[g][h][u][1] * iv;
          val.z = acc[g][h][u][2] * iv;
          val.w = acc[g][h][u][3] * iv;
          *(float4*)(Sg + (size_t)qq * 3200 + r * 128 + h * 64 + 4 * tx) = val;
        }
      }
    }
}

// Phase 2: one block per (b,q). Load S -> softmaxes -> BA -> f64 GE -> outputs.
__global__ __launch_bounds__(256)
void solve_kernel(const float* __restrict__ Sg, float* __restrict__ out) {
  __shared__ float Sld[25 * 131];           // odd stride: conflict-free col reads
  __shared__ float Qm[3125];                // [col][i]
  __shared__ double Msol[675];              // augmented 25x26, stride 27
  __shared__ double xsd[HW];
  __shared__ float kqs[HW];
  __shared__ float ksf[MS];

  const int tid = threadIdx.x;
  const int bq = blockIdx.x;
  const float* src = Sg + (size_t)bq * 3200;
  for (int idx = tid; idx < 3200; idx += 256) {
    const int row = idx >> 7, c = idx & 127;
    Sld[row * 131 + c] = src[idx];          // coalesced global read
  }
  __syncthreads();

  // column softmax with GAMMA2 -> Qm[col][i]
  if (tid < MS) {
    float mx = -1e30f;
    #pragma unroll
    for (int i = 0; i < HW; ++i) mx = fmaxf(mx, Sld[i * 131 + tid]);
    float e[HW]; float sum = 0.f;
    #pragma unroll
    for (int i = 0; i < HW; ++i) { e[i] = __expf(GAMMA2 * (Sld[i * 131 + tid] - mx)); sum += e[i]; }
    float is = 1.f / sum;
    #pragma unroll
    for (int i = 0; i < HW; ++i) Qm[tid * HW + i] = e[i] * is;
  }
  __syncthreads();

  // row softmax with GAMMA, in place -> P
  {
    int i = tid >> 3, s8 = tid & 7;
    if (i < HW) {
      float mx = -1e30f;
      for (int j = s8; j < MS; j += 8) mx = fmaxf(mx, Sld[i * 131 + j]);
      mx = fmaxf(mx, __shfl_xor(mx, 1));
      mx = fmaxf(mx, __shfl_xor(mx, 2));
      mx = fmaxf(mx, __shfl_xor(mx, 4));
      float sum = 0.f;
      for (int j = s8; j < MS; j += 8) {
        float e = __expf(GAMMA * (Sld[i * 131 + j] - mx));
        Sld[i * 131 + j] = e; sum += e;
      }
      sum += __shfl_xor(sum, 1); sum += __shfl_xor(sum, 2); sum += __shfl_xor(sum, 4);
      float is = 1.f / sum;
      for (int j = s8; j < MS; j += 8) Sld[i * 131 + j] *= is;
    }
  }
  __syncthreads();

  // BA (+ B*1 via i2==25) -> Msol
  #pragma unroll
  for (int t = 0; t < 3; ++t) {
    const int pp = tid + 256 * t;
    if (pp < 650) {
      const int i = pp / 26, i2 = pp - 26 * i;
      float s = 0.f;
      if (i2 < 25) {
        for (int j = 0; j < MS; ++j) s += Qm[j * HW + i] * Sld[i2 * 131 + j];
        Msol[i * 27 + i2] = (i == i2 ? 1.0 : 0.0) - 0.998001 * (double)s;
      } else {
        for (int j = 0; j < MS; ++j) s += Qm[j * HW + i];
        Msol[i * 27 + 25] = 1.0 + 0.999 * (double)s;
      }
    }
  }
  __syncthreads();

  // Gaussian elimination, no pivoting (column-diagonally-dominant)
  for (int k = 0; k < 24; ++k) {
    const double invp = 1.0 / Msol[k * 27 + k];
    const int jj = k + 1 + (tid & 31);
    for (int i = k + 1 + (tid >> 5); i < HW; i += 8) {
      const double f = Msol[i * 27 + k] * invp;
      if (jj <= HW) Msol[i * 27 + jj] -= f * Msol[k * 27 + jj];
    }
    __syncthreads();
  }
  for (int k = 24; k >= 0; --k) {
    const double xk = Msol[k * 27 + 25] / Msol[k * 27 + k];
    if (tid == 0) xsd[k] = xk;
    if (tid < k) Msol[tid * 27 + 25] -= Msol[tid * 27 + k] * xk;
    __syncthreads();
  }

  // outputs
  if (tid < HW) kqs[tid] = (float)(xsd[tid] - 1.0);
  if (tid < MS) {
    float a = 0.f;
    #pragma unroll
    for (int i = 0; i < HW; ++i) a += Sld[i * 131 + tid] * (float)xsd[i];
    ksf[tid] = 0.999f * a;
  }
  __syncthreads();
  if (tid < HW) {
    float s = 0.f;
    #pragma unroll
    for (int i = 0; i < HW; ++i) s += kqs[i];
    out[(size_t)bq * HW + tid] = kqs[tid] / s;
  }
  if (tid < MS) {
    const int n = tid / HW;
    float s = 0.f;
    #pragma unroll
    for (int k2 = 0; k2 < HW; ++k2) s += ksf[n * HW + k2];
    out[60000 + (size_t)bq * MS + tid] = ksf[tid] / s;
  }
}

// Fallback (ws too small): r12 proven monolithic kernel (320 us timed).
__global__ __launch_bounds__(256)
void melmask_kernel(const float* __restrict__ qry, const float* __restrict__ sup_t,
                    float* __restrict__ out) {
  __shared__ __align__(16) float pool[4224];
  __shared__ __align__(16) float Sld[3125];
  __shared__ double Msol[675];
  __shared__ double xsd[HW];
  __shared__ float invq_s[128];
  __shared__ float kqs[HW];
  __shared__ float ksf[MS];

  float* atile = pool;
  float* btile = pool + 2112;
  float* Qm    = pool;

  const int tid = threadIdx.x;
  const int Bl = (blockIdx.x & 7) * 60 + (blockIdx.x >> 3);
  const int b = Bl / 15, qg = Bl - 15 * b;
  const float* qbase = qry + ((size_t)b * 75 + (size_t)qg * 5) * CHW;
  const float* sbase = sup_t + (size_t)b * (MS * CH);
  const int ty = tid >> 4, tx = tid & 15;

  float acc[2][2][4][4];
  #pragma unroll
  for (int g = 0; g < 2; ++g)
    #pragma unroll
    for (int h = 0; h < 2; ++h)
      #pragma unroll
      for (int u = 0; u < 4; ++u)
        #pragma unroll
        for (int v = 0; v < 4; ++v) acc[g][h][u][v] = 0.f;
  float npart = 0.f;

  for (int c0 = 0; c0 < CH; c0 += 16) {
    __syncthreads();
    #pragma unroll
    for (int mm = 0; mm < 8; ++mm) {
      int idx = tid + 256 * mm;
      int k = idx >> 7, row = idx & 127;
      float v = 0.f;
      if (row < MS) {
        int qq = row / 25, i = row - 25 * qq;
        v = qbase[(size_t)qq * CHW + (size_t)(c0 + k) * 25 + i];
      }
      atile[k * 132 + row] = v;
    }
    #pragma unroll
    for (int mm = 0; mm < 2; ++mm) {
      int idx = tid + 256 * mm;
      int col = idx >> 2, kq = idx & 3;
      float4 v = make_float4(0.f, 0.f, 0.f, 0.f);
      if (col < MS) v = *(const float4*)(sbase + (size_t)col * CH + c0 + 4 * kq);
      btile[(4 * kq + 0) * 132 + col] = v.x;
      btile[(4 * kq + 1) * 132 + col] = v.y;
      btile[(4 * kq + 2) * 132 + col] = v.z;
      btile[(4 * kq + 3) * 132 + col] = v.w;
    }
    __syncthreads();
    if (tid < MS) {
      #pragma unroll
      for (int k = 0; k < 16; ++k) { float v = atile[k * 132 + tid]; npart += v * v; }
    }
    #pragma unroll
    for (int k = 0; k < 16; ++k) {
      const float4 a0 = *(const float4*)&atile[k * 132 + 4 * ty];
      const float4 a1 = *(const float4*)&atile[k * 132 + 64 + 4 * ty];
      const float4 b0 = *(const float4*)&btile[k * 132 + 4 * tx];
      const float4 b1 = *(const float4*)&btile[k * 132 + 64 + 4 * tx];
      const float ag[2][4] = {{a0.x, a0.y, a0.z, a0.w}, {a1.x, a1.y, a1.z, a1.w}};
      const float bg[2][4] = {{b0.x, b0.y, b0.z, b0.w}, {b1.x, b1.y, b1.z, b1.w}};
      #pragma unroll
      for (int g = 0; g < 2; ++g)
        #pragma unroll
        for (int u = 0; u < 4; ++u)
          #pragma unroll
          for (int h = 0; h < 2; ++h)
            #pragma unroll
            for (int v = 0; v < 4; ++v) acc[g][h][u][v] += ag[g][u] * bg[h][v];
    }
  }
  if (tid < MS) invq_s[tid] = rsqrtf(npart + EPS);
  __syncthreads();

  for (int qq = 0; qq < 5; ++qq) {
    const int bq = b * 75 + qg * 5 + qq;
    const int r0 = qq * 25;
    #pragma unroll
    for (int g = 0; g < 2; ++g)
      #pragma unroll
      for (int u = 0; u < 4; ++u) {
        const int row = g * 64 + 4 * ty + u;
        if (row >= r0 && row < r0 + 25) {
          const int r = row - r0;
          const float iv = invq_s[row];
          #pragma unroll
          for (int h = 0; h < 2; ++h)
            #pragma unroll
            for (int v = 0; v < 4; ++v) {
              const int col = h * 64 + 4 * tx + v;
              if (col < MS) Sld[r * MS + col] = acc[g][h][u][v] * iv;
            }
        }
      }
    __syncthreads();
    if (tid < MS) {
      float mx = -1e30f;
      #pragma unroll
      for (int i = 0; i < HW; ++i) mx = fmaxf(mx, Sld[i * MS + tid]);
      float e[HW]; float sum = 0.f;
      #pragma unroll
      for (int i = 0; i < HW; ++i) { e[i] = __expf(GAMMA2 * (Sld[i * MS + tid] - mx)); sum += e[i]; }
      float is = 1.f / sum;
      #pragma unroll
      for (int i = 0; i < HW; ++i) Qm[tid * HW + i] = e[i] * is;
    }
    __syncthreads();
    {
      int i = tid >> 3, s8 = tid & 7;
      if (i < HW) {
        float mx = -1e30f;
        for (int j = s8; j < MS; j += 8) mx = fmaxf(mx, Sld[i * MS + j]);
        mx = fmaxf(mx, __shfl_xor(mx, 1));
        mx = fmaxf(mx, __shfl_xor(mx, 2));
        mx = fmaxf(mx, __shfl_xor(mx, 4));
        float sum = 0.f;
        for (int j = s8; j < MS; j += 8) {
          float e = __expf(GAMMA * (Sld[i * MS + j] - mx));
          Sld[i * MS + j] = e; sum += e;
        }
        sum += __shfl_xor(sum, 1); sum += __shfl_xor(sum, 2); sum += __shfl_xor(sum, 4);
        float is = 1.f / sum;
        for (int j = s8; j < MS; j += 8) Sld[i * MS + j] *= is;
      }
    }
    __syncthreads();
    float* P = Sld;
    #pragma unroll
    for (int t = 0; t < 3; ++t) {
      const int pp = tid + 256 * t;
      if (pp < 650) {
        const int i = pp / 26, i2 = pp - 26 * i;
        float s = 0.f;
        if (i2 < 25) {
          for (int j = 0; j < MS; ++j) s += Qm[j * HW + i] * P[i2 * MS + j];
          Msol[i * 27 + i2] = (i == i2 ? 1.0 : 0.0) - 0.998001 * (double)s;
        } else {
          for (int j = 0; j < MS; ++j) s += Qm[j * HW + i];
          Msol[i * 27 + 25] = 1.0 + 0.999 * (double)s;
        }
      }
    }
    __syncthreads();
    for (int k = 0; k < 24; ++k) {
      const double invp = 1.0 / Msol[k * 27 + k];
      const int jj = k + 1 + (tid & 31);
      for (int i = k + 1 + (tid >> 5); i < HW; i += 8) {
        const double f = Msol[i * 27 + k] * invp;
        if (jj <= HW) Msol[i * 27 + jj] -= f * Msol[k * 27 + jj];
      }
      __syncthreads();
    }
    for (int k = 24; k >= 0; --k) {
      const double xk = Msol[k * 27 + 25] / Msol[k * 27 + k];
      if (tid == 0) xsd[k] = xk;
      if (tid < k) Msol[tid * 27 + 25] -= Msol[tid * 27 + k] * xk;
      __syncthreads();
    }
    if (tid < HW) kqs[tid] = (float)(xsd[tid] - 1.0);
    if (tid < MS) {
      float a = 0.f;
      #pragma unroll
      for (int i = 0; i < HW; ++i) a += P[i * MS + tid] * (float)xsd[i];
      ksf[tid] = 0.999f * a;
    }
    __syncthreads();
    if (tid < HW) {
      float s = 0.f;
      #pragma unroll
      for (int i = 0; i < HW; ++i) s += kqs[i];
      out[(size_t)bq * HW + tid] = kqs[tid] / s;
    }
    if (tid < MS) {
      const int n = tid / HW;
      float s = 0.f;
      #pragma unroll
      for (int k2 = 0; k2 < HW; ++k2) s += ksf[n * HW + k2];
      out[60000 + (size_t)bq * MS + tid] = ksf[tid] / s;
    }
    __syncthreads();
  }
}

extern "C" void kernel_launch(void* const* d_in, const int* in_sizes, int n_in,
                              void* d_out, int out_size, void* d_ws, size_t ws_size,
                              hipStream_t stream) {
  const float* sup = (const float*)d_in[0];
  const float* qry = (const float*)d_in[1];
  float* outp = (float*)d_out;
  float* sup_t = (float*)d_ws;                       // 10,240,000 B
  prep_sup_kernel<<<160, 256, 0, stream>>>(sup, sup_t);
  const size_t need = 10240000ull + (size_t)2400 * 3200 * 4;  // + 30.72 MB S buffer
  if (ws_size >= need) {
    float* Sg = (float*)((char*)d_ws + 10240000);
    gemm_s_kernel<<<480, 256, 0, stream>>>(qry, sup_t, Sg);
    solve_kernel<<<2400, 256, 0, stream>>>(Sg, outp);
  } else {
    melmask_kernel<<<480, 256, 0, stream>>>(qry, sup_t, outp);
  }
}